// Round 10
// baseline (129.310 us; speedup 1.0000x reference)
//
#include <hip/hip_runtime.h>
#include <math.h>

typedef float fvec4 __attribute__((ext_vector_type(4)));

// ---- DPP cross-lane helpers (VALU, no DS-unit traffic) ----
template <int CTRL, int RM, int BM>
static __device__ __forceinline__ float updf(float oldv, float src) {
  return __int_as_float(__builtin_amdgcn_update_dpp(
      __float_as_int(oldv), __float_as_int(src), CTRL, RM, BM, false));
}

static __device__ __forceinline__ float mul_scan64(float x) {
  x *= updf<0x111, 0xf, 0xf>(1.0f, x);  // row_shr:1
  x *= updf<0x112, 0xf, 0xf>(1.0f, x);  // row_shr:2
  x *= updf<0x114, 0xf, 0xe>(1.0f, x);  // row_shr:4
  x *= updf<0x118, 0xf, 0xc>(1.0f, x);  // row_shr:8
  x *= updf<0x142, 0xa, 0xf>(1.0f, x);  // row_bcast:15 -> rows 1,3
  x *= updf<0x143, 0xc, 0xf>(1.0f, x);  // row_bcast:31 -> rows 2,3
  return x;
}
static __device__ __forceinline__ float sum64_lane63(float x) {
  x += updf<0x111, 0xf, 0xf>(0.0f, x);
  x += updf<0x112, 0xf, 0xf>(0.0f, x);
  x += updf<0x114, 0xf, 0xe>(0.0f, x);
  x += updf<0x118, 0xf, 0xc>(0.0f, x);
  x += updf<0x142, 0xa, 0xf>(0.0f, x);
  x += updf<0x143, 0xc, 0xf>(0.0f, x);
  return x;
}
static __device__ __forceinline__ float readlane63(float x) {
  return __int_as_float(__builtin_amdgcn_readlane(__float_as_int(x), 63));
}

// ws layout:
//   ws[0     .. nb-1 ]  per-block depth min partials
//   ws[nb    .. 2nb-1]  per-block depth max partials
//   cd_ws = ws + 2nb + 64 : raw composite depth per ray

// Kernel 1: fused march + rgb. 256 thr = 4 waves; each wave owns 4 rays.
__global__ __launch_bounds__(256) void fused_kernel(
    const float* __restrict__ colors, const float* __restrict__ dens,
    const float* __restrict__ depths, const float* __restrict__ grads,
    float* __restrict__ out, float* __restrict__ ws, float* __restrict__ cd_ws,
    size_t o_w, size_t o_grad, int nb)
{
  __shared__ float smin[4], smax[4];
  const int lane = threadIdx.x & 63;
  const int wid  = threadIdx.x >> 6;
  const size_t ray0 = (size_t)blockIdx.x * 16 + (size_t)wid * 4;

  float cf[4];
  float dmin_w = INFINITY, dmax_w = -INFINITY;

  // ---- phase A: 4 independent scan chains (ILP across rays) ----
#pragma unroll
  for (int r = 0; r < 4; ++r) {
    const size_t ray = ray0 + r;
    const float d   = __builtin_nontemporal_load(depths + ray * 64 + lane);
    const float den = __builtin_nontemporal_load(dens + ray * 64 + lane);
    const float* gp = grads + ray * 192 + (size_t)lane * 3;
    const float g0 = __builtin_nontemporal_load(gp + 0);
    const float g1 = __builtin_nontemporal_load(gp + 1);
    const float g2 = __builtin_nontemporal_load(gp + 2);

    dmin_w = fminf(dmin_w, d);
    dmax_w = fmaxf(dmax_w, d);

    const float dn    = __shfl_down(d, 1);
    const float denn  = __shfl_down(den, 1);
    const float delta = dn - d;
    const float dm    = 0.5f * (den + denn) - 1.0f;
    const float sp    = fmaxf(dm, 0.0f) + log1pf(expf(-fabsf(dm)));  // softplus
    const float dd    = sp * delta;
    const float alpha = 1.0f - expf(-dd);
    const float t     = (1.0f - alpha) + 1e-10f;

    const float p = mul_scan64(t);
    float excl = __shfl_up(p, 1);
    if (lane == 0) excl = 1.0f;
    const float w = (lane < 63) ? alpha * excl : 0.0f;

    if (lane < 63)
      __builtin_nontemporal_store(w, out + o_w + ray * 63 + lane);

    float wprev = __shfl_up(w, 1);
    if (lane == 0) wprev = 0.0f;
    const float coef = 0.5f * (w + wprev);
    cf[r] = coef;

    const float wt = readlane63(sum64_lane63(w));
    const float s1 = readlane63(sum64_lane63(coef * d));
    const float s2 = readlane63(sum64_lane63(coef * g0));
    const float s3 = readlane63(sum64_lane63(coef * g1));
    const float s4 = readlane63(sum64_lane63(coef * g2));

    if (lane == 0) {
      float cd = s1 / wt;
      if (cd != cd) cd = INFINITY;        // NaN -> inf (clip later -> dmax)
      cd_ws[ray] = cd;
      const float add = 1.0f - wt;
      float* og = out + o_grad + ray * 3;
      __builtin_nontemporal_store(s2 + add, og + 0);
      __builtin_nontemporal_store(s3 + add, og + 1);
      __builtin_nontemporal_store(s4 + add, og + 2);
    }
  }

  // block depth-minmax partial (no atomics)
#pragma unroll
  for (int off = 32; off; off >>= 1) {
    dmin_w = fminf(dmin_w, __shfl_xor(dmin_w, off));
    dmax_w = fmaxf(dmax_w, __shfl_xor(dmax_w, off));
  }
  if (lane == 0) { smin[wid] = dmin_w; smax[wid] = dmax_w; }
  __syncthreads();
  if (threadIdx.x == 0) {
    ws[blockIdx.x]      = fminf(fminf(smin[0], smin[1]), fminf(smin[2], smin[3]));
    ws[nb + blockIdx.x] = fmaxf(fmaxf(smax[0], smax[1]), fmaxf(smax[2], smax[3]));
  }

  // ---- phase B: color streaming + weighted reduce ----
  const int sbase = lane >> 3;
#pragma unroll
  for (int r = 0; r < 4; ++r) {
    const size_t ray = ray0 + r;
    // transposed loads: instr k reads contiguous 1 KB; lane holds
    // sample s = k*8 + (lane>>3), channels (lane&7)*4 .. +3
    const fvec4* cp = (const fvec4*)(colors + ray * 2048);
    fvec4 col[8];
#pragma unroll
    for (int k = 0; k < 8; ++k)
      col[k] = __builtin_nontemporal_load(cp + (size_t)k * 64 + lane);

    float a0 = 0.f, a1 = 0.f, a2 = 0.f, a3 = 0.f;
#pragma unroll
    for (int k = 0; k < 8; ++k) {
      const float cfb = __shfl(cf[r], k * 8 + sbase);
      a0 = fmaf(cfb, col[k].x, a0);
      a1 = fmaf(cfb, col[k].y, a1);
      a2 = fmaf(cfb, col[k].z, a2);
      a3 = fmaf(cfb, col[k].w, a3);
    }
    a0 += updf<0x128, 0xf, 0xf>(0.0f, a0);   // + lane^8 (row_ror:8)
    a1 += updf<0x128, 0xf, 0xf>(0.0f, a1);
    a2 += updf<0x128, 0xf, 0xf>(0.0f, a2);
    a3 += updf<0x128, 0xf, 0xf>(0.0f, a3);
#pragma unroll
    for (int off = 16; off <= 32; off <<= 1) {
      a0 += __shfl_xor(a0, off);
      a1 += __shfl_xor(a1, off);
      a2 += __shfl_xor(a2, off);
      a3 += __shfl_xor(a3, off);
    }
    if (lane < 8) {
      fvec4 o;
      o.x = fmaf(a0, 2.0f, -1.0f);
      o.y = fmaf(a1, 2.0f, -1.0f);
      o.z = fmaf(a2, 2.0f, -1.0f);
      o.w = fmaf(a3, 2.0f, -1.0f);
      __builtin_nontemporal_store(o, (fvec4*)(out + ray * 32) + lane);
    }
  }
}

// Kernel 2: each block redundantly reduces the 2*nb partials (L2-hot),
// then clips its 256 rays' depths. No extra reduce dispatch.
__global__ __launch_bounds__(256) void depth_kernel(
    const float* __restrict__ cd_ws, const float* __restrict__ ws,
    float* __restrict__ out, size_t o_depth, int nb)
{
  __shared__ float smin[4], smax[4];
  float m0 = INFINITY, m1 = -INFINITY;
  for (int j = threadIdx.x; j < nb; j += 256) {
    m0 = fminf(m0, ws[j]);
    m1 = fmaxf(m1, ws[nb + j]);
  }
#pragma unroll
  for (int off = 32; off; off >>= 1) {
    m0 = fminf(m0, __shfl_xor(m0, off));
    m1 = fmaxf(m1, __shfl_xor(m1, off));
  }
  const int wid = threadIdx.x >> 6;
  if ((threadIdx.x & 63) == 0) { smin[wid] = m0; smax[wid] = m1; }
  __syncthreads();
  const float dmin = fminf(fminf(smin[0], smin[1]), fminf(smin[2], smin[3]));
  const float dmax = fmaxf(fmaxf(smax[0], smax[1]), fmaxf(smax[2], smax[3]));

  const int i = blockIdx.x * 256 + threadIdx.x;
  out[o_depth + i] = fminf(fmaxf(cd_ws[i], dmin), dmax);
}

extern "C" void kernel_launch(void* const* d_in, const int* in_sizes, int n_in,
                              void* d_out, int out_size, void* d_ws, size_t ws_size,
                              hipStream_t stream) {
  const float* colors = (const float*)d_in[0];
  const float* dens   = (const float*)d_in[1];
  const float* depths = (const float*)d_in[2];
  const float* grads  = (const float*)d_in[3];
  float* out = (float*)d_out;
  float* ws  = (float*)d_ws;

  const int ndep  = in_sizes[2];        // B*R*S = nrays*64
  const int nrays = ndep / 64;          // 65536
  const int C     = in_sizes[0] / ndep; // 32

  const size_t o_depth = (size_t)nrays * C;
  const size_t o_w     = o_depth + (size_t)nrays;
  const size_t o_grad  = o_w + (size_t)nrays * 63;

  const int nb = nrays / 16;            // fused blocks (4096)
  float* cd_ws = ws + 2 * (size_t)nb + 64;

  hipLaunchKernelGGL(fused_kernel, dim3(nb), dim3(256), 0, stream,
                     colors, dens, depths, grads, out, ws, cd_ws, o_w, o_grad, nb);
  hipLaunchKernelGGL(depth_kernel, dim3(nrays / 256), dim3(256), 0, stream,
                     cd_ws, ws, out, o_depth, nb);
}

// Round 11
// 123.711 us; speedup vs baseline: 1.0453x; 1.0453x over previous
//
#include <hip/hip_runtime.h>
#include <math.h>

typedef float fvec4 __attribute__((ext_vector_type(4)));

// ---- DPP cross-lane helpers (VALU, no DS-unit traffic) ----
template <int CTRL, int RM, int BM>
static __device__ __forceinline__ float updf(float oldv, float src) {
  return __int_as_float(__builtin_amdgcn_update_dpp(
      __float_as_int(oldv), __float_as_int(src), CTRL, RM, BM, false));
}

static __device__ __forceinline__ float mul_scan64(float x) {
  x *= updf<0x111, 0xf, 0xf>(1.0f, x);  // row_shr:1
  x *= updf<0x112, 0xf, 0xf>(1.0f, x);  // row_shr:2
  x *= updf<0x114, 0xf, 0xe>(1.0f, x);  // row_shr:4
  x *= updf<0x118, 0xf, 0xc>(1.0f, x);  // row_shr:8
  x *= updf<0x142, 0xa, 0xf>(1.0f, x);  // row_bcast:15 -> rows 1,3
  x *= updf<0x143, 0xc, 0xf>(1.0f, x);  // row_bcast:31 -> rows 2,3
  return x;
}
static __device__ __forceinline__ float sum64_lane63(float x) {
  x += updf<0x111, 0xf, 0xf>(0.0f, x);
  x += updf<0x112, 0xf, 0xf>(0.0f, x);
  x += updf<0x114, 0xf, 0xe>(0.0f, x);
  x += updf<0x118, 0xf, 0xc>(0.0f, x);
  x += updf<0x142, 0xa, 0xf>(0.0f, x);
  x += updf<0x143, 0xc, 0xf>(0.0f, x);
  return x;
}
static __device__ __forceinline__ float readlane63(float x) {
  return __int_as_float(__builtin_amdgcn_readlane(__float_as_int(x), 63));
}

// ws layout: ws[0..511] block depth-min partials, ws[512..1023] block max partials.

// Kernel 1: depth min/max partials, 512 blocks, no atomics. Plain loads so
// depths linger in L2/L3 for the fused kernel's re-read.
__global__ __launch_bounds__(256) void minmax_kernel(const float4* __restrict__ d,
                                                     float* __restrict__ ws, int n4) {
  __shared__ float smin[4], smax[4];
  int idx = blockIdx.x * 256 + threadIdx.x;
  int stride = gridDim.x * 256;
  float lmin = INFINITY, lmax = -INFINITY;
  for (int i = idx; i < n4; i += stride) {
    float4 v = d[i];
    lmin = fminf(lmin, fminf(fminf(v.x, v.y), fminf(v.z, v.w)));
    lmax = fmaxf(lmax, fmaxf(fmaxf(v.x, v.y), fmaxf(v.z, v.w)));
  }
#pragma unroll
  for (int off = 32; off; off >>= 1) {
    lmin = fminf(lmin, __shfl_xor(lmin, off));
    lmax = fmaxf(lmax, __shfl_xor(lmax, off));
  }
  const int wid = threadIdx.x >> 6;
  if ((threadIdx.x & 63) == 0) { smin[wid] = lmin; smax[wid] = lmax; }
  __syncthreads();
  if (threadIdx.x == 0) {
    ws[blockIdx.x]       = fminf(fminf(smin[0], smin[1]), fminf(smin[2], smin[3]));
    ws[512 + blockIdx.x] = fmaxf(fmaxf(smax[0], smax[1]), fmaxf(smax[2], smax[3]));
  }
}

// Kernel 2: fused march + rgb + final clipped depth. 256 thr = 4 waves; each
// wave owns 4 rays. Prologue reduces the 1024 minmax partials (L2-hot).
__global__ __launch_bounds__(256) void fused_kernel(
    const float* __restrict__ colors, const float* __restrict__ dens,
    const float* __restrict__ depths, const float* __restrict__ grads,
    float* __restrict__ out, const float* __restrict__ mm_part,
    size_t o_depth, size_t o_w, size_t o_grad)
{
  __shared__ float smin[4], smax[4];
  const int lane = threadIdx.x & 63;
  const int wid  = threadIdx.x >> 6;
  const size_t ray0 = (size_t)blockIdx.x * 16 + (size_t)wid * 4;

  // ---- prologue: block-level reduce of 512+512 minmax partials (4 KB) ----
  {
    float m0 = fminf(mm_part[threadIdx.x], mm_part[threadIdx.x + 256]);
    float m1 = fmaxf(mm_part[512 + threadIdx.x], mm_part[512 + threadIdx.x + 256]);
#pragma unroll
    for (int off = 32; off; off >>= 1) {
      m0 = fminf(m0, __shfl_xor(m0, off));
      m1 = fmaxf(m1, __shfl_xor(m1, off));
    }
    if (lane == 0) { smin[wid] = m0; smax[wid] = m1; }
  }
  __syncthreads();
  const float dmin = fminf(fminf(smin[0], smin[1]), fminf(smin[2], smin[3]));
  const float dmax = fmaxf(fmaxf(smax[0], smax[1]), fmaxf(smax[2], smax[3]));

  float cf[4];

  // ---- phase A: 4 independent scan chains (ILP across rays) ----
#pragma unroll
  for (int r = 0; r < 4; ++r) {
    const size_t ray = ray0 + r;
    const float d   = depths[ray * 64 + lane];
    const float den = __builtin_nontemporal_load(dens + ray * 64 + lane);
    const float* gp = grads + ray * 192 + (size_t)lane * 3;
    const float g0 = __builtin_nontemporal_load(gp + 0);
    const float g1 = __builtin_nontemporal_load(gp + 1);
    const float g2 = __builtin_nontemporal_load(gp + 2);

    const float dn    = __shfl_down(d, 1);
    const float denn  = __shfl_down(den, 1);
    const float delta = dn - d;
    const float dm    = 0.5f * (den + denn) - 1.0f;
    const float sp    = fmaxf(dm, 0.0f) + log1pf(expf(-fabsf(dm)));  // softplus
    const float dd    = sp * delta;
    const float alpha = 1.0f - expf(-dd);
    const float t     = (1.0f - alpha) + 1e-10f;

    const float p = mul_scan64(t);
    float excl = __shfl_up(p, 1);
    if (lane == 0) excl = 1.0f;
    const float w = (lane < 63) ? alpha * excl : 0.0f;

    if (lane < 63)
      __builtin_nontemporal_store(w, out + o_w + ray * 63 + lane);

    float wprev = __shfl_up(w, 1);
    if (lane == 0) wprev = 0.0f;
    const float coef = 0.5f * (w + wprev);
    cf[r] = coef;

    const float wt = readlane63(sum64_lane63(w));
    const float s1 = readlane63(sum64_lane63(coef * d));
    const float s2 = readlane63(sum64_lane63(coef * g0));
    const float s3 = readlane63(sum64_lane63(coef * g1));
    const float s4 = readlane63(sum64_lane63(coef * g2));

    if (lane == 0) {
      float cd = s1 / wt;
      if (cd != cd) cd = INFINITY;        // NaN -> inf (clip -> dmax)
      out[o_depth + ray] = fminf(fmaxf(cd, dmin), dmax);
      const float add = 1.0f - wt;
      float* og = out + o_grad + ray * 3;
      og[0] = s2 + add;
      og[1] = s3 + add;
      og[2] = s4 + add;
    }
  }

  // ---- phase B: color streaming + weighted reduce ----
  const int sbase = lane >> 3;
#pragma unroll
  for (int r = 0; r < 4; ++r) {
    const size_t ray = ray0 + r;
    // transposed loads: instr k reads contiguous 1 KB; lane holds
    // sample s = k*8 + (lane>>3), channels (lane&7)*4 .. +3
    const fvec4* cp = (const fvec4*)(colors + ray * 2048);
    fvec4 col[8];
#pragma unroll
    for (int k = 0; k < 8; ++k)
      col[k] = __builtin_nontemporal_load(cp + (size_t)k * 64 + lane);

    float a0 = 0.f, a1 = 0.f, a2 = 0.f, a3 = 0.f;
#pragma unroll
    for (int k = 0; k < 8; ++k) {
      const float cfb = __shfl(cf[r], k * 8 + sbase);
      a0 = fmaf(cfb, col[k].x, a0);
      a1 = fmaf(cfb, col[k].y, a1);
      a2 = fmaf(cfb, col[k].z, a2);
      a3 = fmaf(cfb, col[k].w, a3);
    }
    a0 += updf<0x128, 0xf, 0xf>(0.0f, a0);   // + lane^8 (row_ror:8)
    a1 += updf<0x128, 0xf, 0xf>(0.0f, a1);
    a2 += updf<0x128, 0xf, 0xf>(0.0f, a2);
    a3 += updf<0x128, 0xf, 0xf>(0.0f, a3);
#pragma unroll
    for (int off = 16; off <= 32; off <<= 1) {
      a0 += __shfl_xor(a0, off);
      a1 += __shfl_xor(a1, off);
      a2 += __shfl_xor(a2, off);
      a3 += __shfl_xor(a3, off);
    }
    if (lane < 8) {
      float4 o;
      o.x = fmaf(a0, 2.0f, -1.0f);
      o.y = fmaf(a1, 2.0f, -1.0f);
      o.z = fmaf(a2, 2.0f, -1.0f);
      o.w = fmaf(a3, 2.0f, -1.0f);
      ((float4*)(out + ray * 32))[lane] = o;
    }
  }
}

extern "C" void kernel_launch(void* const* d_in, const int* in_sizes, int n_in,
                              void* d_out, int out_size, void* d_ws, size_t ws_size,
                              hipStream_t stream) {
  const float* colors = (const float*)d_in[0];
  const float* dens   = (const float*)d_in[1];
  const float* depths = (const float*)d_in[2];
  const float* grads  = (const float*)d_in[3];
  float* out = (float*)d_out;
  float* ws  = (float*)d_ws;

  const int ndep  = in_sizes[2];        // B*R*S = nrays*64
  const int nrays = ndep / 64;          // 65536
  const int C     = in_sizes[0] / ndep; // 32

  const size_t o_depth = (size_t)nrays * C;
  const size_t o_w     = o_depth + (size_t)nrays;
  const size_t o_grad  = o_w + (size_t)nrays * 63;

  hipLaunchKernelGGL(minmax_kernel, dim3(512), dim3(256), 0, stream,
                     (const float4*)depths, ws, ndep / 4);
  hipLaunchKernelGGL(fused_kernel, dim3(nrays / 16), dim3(256), 0, stream,
                     colors, dens, depths, grads, out, ws, o_depth, o_w, o_grad);
}